// Round 13
// baseline (819.577 us; speedup 1.0000x reference)
//
#include <hip/hip_runtime.h>
#include <math.h>

typedef unsigned short u16;
typedef unsigned int u32;
typedef short v8s __attribute__((ext_vector_type(8)));
typedef float v4f __attribute__((ext_vector_type(4)));

#define EMB 300
#define SP 320            // padded feature stride (bf16 elems)
#define NGRP 4096
#define FEAT 256
#define MT 128
#define NT 160
#define NCOMB 357         // 119 atom types x 3 chirality
#define NREP 32           // colstats replicas (atomic spread)

__device__ __forceinline__ u16 f2bf(float x) {
    u32 u = __float_as_uint(x);
    u += 0x7FFFu + ((u >> 16) & 1u);
    return (u16)(u >> 16);
}
__device__ __forceinline__ float bf2f(u16 h) {
    return __uint_as_float((u32)h << 16);
}
__device__ __forceinline__ void unpack8(uint4 w, float* o) {
    const u32* p = &w.x;
#pragma unroll
    for (int q = 0; q < 4; q++) {
        o[2 * q]     = __uint_as_float(p[q] << 16);
        o[2 * q + 1] = __uint_as_float(p[q] & 0xFFFF0000u);
    }
}
// clamp 8 packed bf16 against per-col bf16-exact thresholds (lossless repack)
__device__ __forceinline__ v8s clampA(uint4 w, float4 ta, float4 tb) {
    const u32* p = &w.x;
    float t[8] = {ta.x, ta.y, ta.z, ta.w, tb.x, tb.y, tb.z, tb.w};
    u32 o[4];
#pragma unroll
    for (int q = 0; q < 4; q++) {
        float lo = __uint_as_float(p[q] << 16);
        float hi = __uint_as_float(p[q] & 0xFFFF0000u);
        lo = fmaxf(lo, t[2 * q]);
        hi = fmaxf(hi, t[2 * q + 1]);
        o[q] = (__float_as_uint(lo) >> 16) | (__float_as_uint(hi) & 0xFFFF0000u);
    }
    uint4 r = make_uint4(o[0], o[1], o[2], o[3]);
    return *(v8s*)&r;
}
// async global->LDS DMA, 16B per lane (dest = wave-uniform base + lane*16)
__device__ __forceinline__ void dma16(const u16* g, u16* l) {
    __builtin_amdgcn_global_load_lds(
        (const __attribute__((address_space(1))) unsigned int*)g,
        (__attribute__((address_space(3))) unsigned int*)l, 16, 0, 0);
}

// ------------------- per-node prep: c9 map + zero deg/cursor ------------------
__global__ void k_prep_n(const int* __restrict__ at, const int* __restrict__ ch,
                         int* __restrict__ c9, int* __restrict__ deg,
                         int* __restrict__ cursor, int N) {
    int n = blockIdx.x * blockDim.x + threadIdx.x;
    if (n < N) {
        c9[n] = at[n] * 3 + ch[n];
        deg[n] = 0;
        cursor[n] = 0;
    }
}

// ------------------- CSR build -------------------
__global__ void k_count(const int* __restrict__ col, int* __restrict__ deg, int E) {
    int e = blockIdx.x * blockDim.x + threadIdx.x;
    if (e < E) atomicAdd(&deg[col[e]], 1);
}

__global__ __launch_bounds__(256) void k_bsum(const int* __restrict__ deg,
                                              int* __restrict__ bsum, int N) {
    int base = blockIdx.x * 1024 + threadIdx.x * 4;
    int s = 0;
    if (base + 3 < N) {
        int4 v = *(const int4*)(deg + base);
        s = v.x + v.y + v.z + v.w;
    } else {
        for (int j = 0; j < 4; j++) if (base + j < N) s += deg[base + j];
    }
    __shared__ int red[256];
    red[threadIdx.x] = s;
    __syncthreads();
    for (int off = 128; off > 0; off >>= 1) {
        if (threadIdx.x < off) red[threadIdx.x] += red[threadIdx.x + off];
        __syncthreads();
    }
    if (threadIdx.x == 0) bsum[blockIdx.x] = red[0];
}

__global__ __launch_bounds__(128) void k_scanb(const int* __restrict__ bsum,
                                               int* __restrict__ boff, int NB) {
    __shared__ int sh[128];
    int t = threadIdx.x;
    int v = (t < NB) ? bsum[t] : 0;
    sh[t] = v;
    __syncthreads();
    for (int off = 1; off < 128; off <<= 1) {
        int add = (t >= off) ? sh[t - off] : 0;
        __syncthreads();
        sh[t] += add;
        __syncthreads();
    }
    if (t < NB) boff[t] = sh[t] - v;
}

__global__ __launch_bounds__(256) void k_indptr(const int* __restrict__ deg,
                                                const int* __restrict__ boff,
                                                int* __restrict__ indptr, int N) {
    int b = blockIdx.x, t = threadIdx.x;
    int base = b * 1024 + t * 4;
    int v[4] = {0, 0, 0, 0};
    if (base + 3 < N) {
        int4 w = *(const int4*)(deg + base);
        v[0] = w.x; v[1] = w.y; v[2] = w.z; v[3] = w.w;
    } else {
        for (int j = 0; j < 4; j++) if (base + j < N) v[j] = deg[base + j];
    }
    int tsum = v[0] + v[1] + v[2] + v[3];
    __shared__ int sh[256];
    sh[t] = tsum;
    __syncthreads();
    for (int off = 1; off < 256; off <<= 1) {
        int add = (t >= off) ? sh[t - off] : 0;
        __syncthreads();
        sh[t] += add;
        __syncthreads();
    }
    int run = boff[b] + sh[t] - tsum;
    for (int j = 0; j < 4; j++) {
        run += v[j];
        if (base + j < N) indptr[base + j + 1] = run;
    }
    if (b == 0 && t == 0) indptr[0] = 0;
}

__global__ void k_fill(const int* __restrict__ row, const int* __restrict__ col,
                       const int* __restrict__ et, const int* __restrict__ ed,
                       const int* __restrict__ indptr, int* __restrict__ cursor,
                       int* __restrict__ packed, int E) {
    int e = blockIdx.x * blockDim.x + threadIdx.x;
    if (e >= E) return;
    int c = col[e];
    int pos = indptr[c] + atomicAdd(&cursor[c], 1);
    packed[pos] = row[e] | ((et[e] * 3 + ed[e]) << 17);
}

// ------------------- comb table: comb[at*3+ch] = bf16(e1[at] + e2[ch]) --------
__global__ void k_comb(const float* __restrict__ e1, const float* __restrict__ e2,
                       u16* __restrict__ comb) {
    int idx = blockIdx.x * blockDim.x + threadIdx.x;
    if (idx >= NCOMB * 40) return;
    int row = idx / 40, f = idx % 40;
    int at = row / 3, ch = row % 3;
    u32 o[4];
#pragma unroll
    for (int q = 0; q < 4; q++) {
        int c0 = f * 8 + q * 2;
        float x0 = 0.f, x1 = 0.f;
        if (c0 < EMB)     x0 = e1[(size_t)at * EMB + c0] + e2[(size_t)ch * EMB + c0];
        if (c0 + 1 < EMB) x1 = e1[(size_t)at * EMB + c0 + 1] + e2[(size_t)ch * EMB + c0 + 1];
        o[q] = (u32)f2bf(x0) | ((u32)f2bf(x1) << 16);
    }
    *(uint4*)(comb + (size_t)row * SP + f * 8) = make_uint4(o[0], o[1], o[2], o[3]);
}

// ------------------- merged W prep: Wt + srow (one W-column read) -------------
__global__ __launch_bounds__(320) void k_wprep(
    const float* __restrict__ Wl, const float* __restrict__ sc,
    const float* __restrict__ sh, u16* __restrict__ Wt, float* __restrict__ srow) {
    __shared__ float wred[5];
    int n = blockIdx.x;
    int k = threadIdx.x;
    float w = 0.f;
    if (n < EMB && k < EMB) w = Wl[(size_t)k * EMB + n];
    Wt[(size_t)n * SP + k] = f2bf(w * sc[k]);
    float s = (k < EMB) ? sh[k] * w : 0.f;
#pragma unroll
    for (int o2 = 32; o2 > 0; o2 >>= 1) s += __shfl_down(s, o2);
    if ((k & 63) == 0) wred[k >> 6] = s;
    __syncthreads();
    if (k == 0) {
        float t = wred[0] + wred[1] + wred[2] + wred[3] + wred[4];
        srow[n] = (n < EMB) ? t : 0.f;
    }
}

// ------------------- identity (layer 0) / BN-finalize -------------------------
// k_ident zeroes all NREP colstats replicas.
__global__ void k_ident(float* __restrict__ sc, float* __restrict__ sh,
                        float* __restrict__ thr, float* __restrict__ colstats) {
    int c = threadIdx.x;
    if (c < SP) {
        sc[c] = (c < EMB) ? 1.f : 0.f;
        sh[c] = 0.f;
        thr[c] = -__builtin_inff();
        for (int r = 0; r < NREP; r++) {
            colstats[r * 2 * SP + c] = 0.f;
            colstats[r * 2 * SP + SP + c] = 0.f;
        }
    }
}

// sums the NREP replicas, computes BN scale/shift/threshold, re-zeros replicas.
__global__ void k_finalize(float* __restrict__ cs,
                           const float* __restrict__ gamma, const float* __restrict__ beta,
                           float* __restrict__ sc, float* __restrict__ sh,
                           float* __restrict__ thr, int N) {
    int c = threadIdx.x;
    if (c >= SP) return;
    float s1 = 0.f, s2 = 0.f;
    for (int r = 0; r < NREP; r++) {
        s1 += cs[r * 2 * SP + c];
        s2 += cs[r * 2 * SP + SP + c];
        cs[r * 2 * SP + c] = 0.f;
        cs[r * 2 * SP + SP + c] = 0.f;
    }
    if (c < EMB) {
        float inv = 1.f / (float)N;
        float mean = s1 * inv;
        float var = s2 * inv - mean * mean;
        float rstd = rsqrtf(fmaxf(var, 0.f) + 1e-5f);
        float s = gamma[c] * rstd;
        float b = beta[c] - mean * s;
        sc[c] = s;
        sh[c] = b;
        thr[c] = bf2f(f2bf(-b / s));
    } else {
        sc[c] = 0.f; sh[c] = 0.f; thr[c] = -__builtin_inff();
    }
}

// ------------------- GEMM: Q = max(A[rowmap], thr) @ Wt + srow  ---------------
// A via DMA double-buffer (16 KB LDS); B fragments read directly global->VGPR
// (per-n-half B slice is 100 KB, L2-resident, shared by all blocks). Epilogue
// in two 64-row passes (21.5 KB overlay). LDS total 21.5 KB -> ~6 blocks/CU
// (vs 3 at the old 43 KB), and the Bs-read bank conflicts disappear.
__global__ __launch_bounds__(256) void k_gemm(
    const u16* __restrict__ A, const u16* __restrict__ Wt,
    const float* __restrict__ thr, const float* __restrict__ srow,
    u16* __restrict__ C, int M, const int* __restrict__ rowmap) {
    __shared__ __align__(16) u16 sm[10752];   // As dbuf 2x4096 u16; epi 64x168

    int m0 = blockIdx.y * MT;
    int n0 = blockIdx.x * NT;
    int tid = threadIdx.x;
    int wave = tid >> 6, lane = tid & 63;
    int wm = wave >> 1, wn = wave & 1;
    int lm = lane & 15, quad = lane >> 4;

    int ar0 = min(m0 + (tid >> 2), M - 1);
    int ar1 = min(m0 + 64 + (tid >> 2), M - 1);
    if (rowmap) { ar0 = rowmap[ar0]; ar1 = rowmap[ar1]; }
    const u16* ag0 = A + (size_t)ar0 * SP + (tid & 3) * 8;
    const u16* ag1 = A + (size_t)ar1 * SP + (tid & 3) * 8;
    const u16* bp = Wt + (size_t)(n0 + wn * 80 + lm) * SP + quad * 8;

    const float* tp = thr + quad * 8;

    v4f acc[4][5];
#pragma unroll
    for (int nf = 0; nf < 5; nf++) {
        float sv = srow[n0 + wn * 80 + nf * 16 + lm];
#pragma unroll
        for (int mf = 0; mf < 4; mf++)
            acc[mf][nf] = (v4f){sv, sv, sv, sv};
    }

    auto issue = [&](int d, int kt) {
        int ko = kt * 32;
        u16* ad = sm + d * 4096;
        dma16(ag0 + ko, ad + tid * 8);
        dma16(ag1 + ko, ad + (256 + tid) * 8);
    };

    issue(0, 0);
    for (int kt = 0; kt < SP / 32; kt++) {
        __syncthreads();                      // drains this ktile's A-DMA
        if (kt + 1 < SP / 32) issue((kt + 1) & 1, kt + 1);
        const u16* as = sm + (kt & 1) * 4096;
        float4 ta = *(const float4*)(tp + kt * 32);
        float4 tb = *(const float4*)(tp + kt * 32 + 4);
        v8s b[5], a[4];
#pragma unroll
        for (int nf = 0; nf < 5; nf++)
            b[nf] = *(const v8s*)(bp + (size_t)nf * 16 * SP + kt * 32);
#pragma unroll
        for (int mf = 0; mf < 4; mf++) {
            uint4 w = *(const uint4*)(as + (wm * 64 + mf * 16 + lm) * 32 + quad * 8);
            a[mf] = clampA(w, ta, tb);
        }
#pragma unroll
        for (int nf = 0; nf < 5; nf++)
#pragma unroll
            for (int mf = 0; mf < 4; mf++)
                acc[mf][nf] = __builtin_amdgcn_mfma_f32_16x16x32_bf16(a[mf], b[nf], acc[mf][nf], 0, 0, 0);
    }

    __syncthreads();                          // staging reads done -> overlay
    // epilogue: two 64-row passes through the 64x168 overlay
#pragma unroll
    for (int p = 0; p < 2; p++) {
#pragma unroll
        for (int mf2 = 0; mf2 < 2; mf2++) {
            int mf = p * 2 + mf2;
#pragma unroll
            for (int nf = 0; nf < 5; nf++)
#pragma unroll
                for (int r = 0; r < 4; r++)
                    sm[(wm * 32 + mf2 * 16 + quad * 4 + r) * 168 + wn * 80 + nf * 16 + lm] =
                        f2bf(acc[mf][nf][r]);
        }
        __syncthreads();
#pragma unroll
        for (int i = 0; i < 5; i++) {
            int slot = tid + i * 256;         // 1280 slots = 64 rows x 20 cgroups
            int lr = slot / 20, cg = slot % 20;
            int grow = m0 + (lr >> 5) * 64 + p * 32 + (lr & 31);
            if (grow < M)
                *(uint4*)(C + (size_t)grow * SP + n0 + cg * 8) =
                    *(const uint4*)(sm + lr * 168 + cg * 8);
        }
        __syncthreads();
    }
}

// ------------------- aggregate + fused BN stats, flat one-node-per-slot -------
__global__ __launch_bounds__(320) void k_aggf(
    const u16* __restrict__ Q, const int* __restrict__ indptr,
    const int* __restrict__ packed, const float* __restrict__ e1,
    const float* __restrict__ e2, u16* __restrict__ P,
    float* __restrict__ colstats, int N) {
    __shared__ float tab[15];
    __shared__ float part[8][328];
    int tid = threadIdx.x;
    if (tid < 15) tab[tid] = e1[tid / 3] + e2[tid % 3];
    __syncthreads();
    int f = tid % 40;
    int slot = tid / 40;
    int n = blockIdx.x * 8 + slot;

    float psum[8] = {0, 0, 0, 0, 0, 0, 0, 0};
    float psq[8]  = {0, 0, 0, 0, 0, 0, 0, 0};

    if (n < N) {
        float acc[8];
        unpack8(*(const uint4*)(Q + (size_t)n * SP + f * 8), acc);
        float s = tab[12];                  // self loop: et=4, ed=0 -> code 12
        int i = indptr[n], e = indptr[n + 1];
        int pk = (i < e) ? packed[i] : 0;
        while (i < e) {
            uint4 g = *(const uint4*)(Q + (size_t)(pk & 0x1FFFF) * SP + f * 8);
            int nx = i + 1;
            int pkn = (nx < e) ? packed[nx] : 0;
            float t[8];
            unpack8(g, t);
#pragma unroll
            for (int q = 0; q < 8; q++) acc[q] += t[q];
            s += tab[pk >> 17];
            i = nx; pk = pkn;
        }
        u32 o[4];
#pragma unroll
        for (int q = 0; q < 4; q++) {
            float r0 = acc[2 * q] + s;
            float r1 = acc[2 * q + 1] + s;
            psum[2 * q] = r0;      psum[2 * q + 1] = r1;
            psq[2 * q]  = r0 * r0; psq[2 * q + 1]  = r1 * r1;
            o[q] = (u32)f2bf(r0) | ((u32)f2bf(r1) << 16);
        }
        *(uint4*)(P + (size_t)n * SP + f * 8) = make_uint4(o[0], o[1], o[2], o[3]);
    }

    int rep = (blockIdx.x & (NREP - 1)) * 2 * SP;
#pragma unroll
    for (int j = 0; j < 8; j++) part[slot][f * 8 + j] = psum[j];
    __syncthreads();
    {
        float s = 0.f;
#pragma unroll
        for (int k = 0; k < 8; k++) s += part[k][tid];
        atomicAdd(&colstats[rep + tid], s);
    }
    __syncthreads();
#pragma unroll
    for (int j = 0; j < 8; j++) part[slot][f * 8 + j] = psq[j];
    __syncthreads();
    {
        float s = 0.f;
#pragma unroll
        for (int k = 0; k < 8; k++) s += part[k][tid];
        atomicAdd(&colstats[rep + SP + tid], s);
    }
}

// ------------------- group boundaries from sorted batch -------------------
__global__ void k_bounds(const int* __restrict__ batch, int* __restrict__ gstart, int N) {
    int n = blockIdx.x * blockDim.x + threadIdx.x;
    if (n > N) return;
    int bcur = (n < N) ? batch[n] : NGRP;
    int bprev = (n > 0) ? batch[n - 1] : -1;
    for (int g = bprev + 1; g <= bcur; g++) gstart[g] = n;
}

// ------------------- pool (BN layer4 fused, no relu), 8 groups/block ----------
__global__ __launch_bounds__(320) void k_pool(
    const u16* __restrict__ P, const float* __restrict__ sc,
    const float* __restrict__ sh, const int* __restrict__ gstart,
    float* __restrict__ hg) {
    int tid = threadIdx.x;
    int g = blockIdx.x * 8 + tid / 40;
    int f = tid % 40;
    int r0 = gstart[g], r1 = gstart[g + 1];
    int cnt = r1 - r0;
    float acc[8] = {0, 0, 0, 0, 0, 0, 0, 0};
    for (int r = r0; r < r1; r++) {
        float t[8];
        unpack8(*(const uint4*)(P + (size_t)r * SP + f * 8), t);
#pragma unroll
        for (int j = 0; j < 8; j++) acc[j] += t[j];
    }
    float inv = 1.f / (float)max(cnt, 1);
#pragma unroll
    for (int j = 0; j < 8; j++) {
        int c = f * 8 + j;
        if (c < EMB)
            hg[(size_t)g * EMB + c] = (acc[j] * sc[c] + (float)cnt * sh[c]) * inv;
    }
}

// ------------------- hf = hg @ feat_W + feat_b -------------------
__global__ __launch_bounds__(256) void k_feat(const float* __restrict__ hg,
                                              const float* __restrict__ fW,
                                              const float* __restrict__ fb,
                                              float* __restrict__ hf) {
    __shared__ float hgs[16 * EMB];
    int g0 = blockIdx.x * 16;
    int tid = threadIdx.x;
    for (int i = tid; i < 16 * EMB; i += 256) {
        int gi = i / EMB, c = i % EMB;
        hgs[i] = hg[(size_t)(g0 + gi) * EMB + c];
    }
    __syncthreads();
    float acc[16];
    float fbv = fb[tid];
#pragma unroll
    for (int gi = 0; gi < 16; gi++) acc[gi] = fbv;
    for (int k = 0; k < EMB; k++) {
        float w = fW[(size_t)k * FEAT + tid];
#pragma unroll
        for (int gi = 0; gi < 16; gi++) acc[gi] += hgs[gi * EMB + k] * w;
    }
#pragma unroll
    for (int gi = 0; gi < 16; gi++) hf[(size_t)(g0 + gi) * FEAT + tid] = acc[gi];
}

// ------------------- head: pred = softplus(hf@W1+b1)@W2+b2 -------------------
__global__ __launch_bounds__(128) void k_head(const float* __restrict__ hf,
                                              const float* __restrict__ W1,
                                              const float* __restrict__ b1,
                                              const float* __restrict__ W2,
                                              const float* __restrict__ b2,
                                              float* __restrict__ pred) {
    __shared__ float hfs[8 * FEAT];
    __shared__ float sred[2][8][2];
    int g0 = blockIdx.x * 8;
    int tid = threadIdx.x;
    for (int i = tid; i < 8 * FEAT; i += 128) {
        int gi = i >> 8, k = i & 255;
        hfs[i] = hf[(size_t)(g0 + gi) * FEAT + k];
    }
    __syncthreads();
    float acc[8];
    float b1v = b1[tid];
#pragma unroll
    for (int gi = 0; gi < 8; gi++) acc[gi] = b1v;
    for (int k = 0; k < FEAT; k++) {
        float w = W1[(size_t)k * 128 + tid];
#pragma unroll
        for (int gi = 0; gi < 8; gi++) acc[gi] += hfs[gi * FEAT + k] * w;
    }
    float w20 = W2[tid * 2], w21 = W2[tid * 2 + 1];
    int wv = tid >> 6;
#pragma unroll
    for (int gi = 0; gi < 8; gi++) {
        float x = acc[gi];
        float t = fmaxf(x, 0.f) + log1pf(expf(-fabsf(x)));
        float p0 = t * w20, p1 = t * w21;
#pragma unroll
        for (int off = 32; off > 0; off >>= 1) {
            p0 += __shfl_down(p0, off);
            p1 += __shfl_down(p1, off);
        }
        if ((tid & 63) == 0) { sred[wv][gi][0] = p0; sred[wv][gi][1] = p1; }
    }
    __syncthreads();
    if (tid < 16) {
        int gi = tid >> 1, o = tid & 1;
        pred[(size_t)(g0 + gi) * 2 + o] = sred[0][gi][o] + sred[1][gi][o] + b2[o];
    }
}

// ------------------- launch -------------------
extern "C" void kernel_launch(void* const* d_in, const int* in_sizes, int n_in,
                              void* d_out, int out_size, void* d_ws, size_t ws_size,
                              hipStream_t stream) {
    const int* atom_type = (const int*)d_in[0];
    const int* chir      = (const int*)d_in[1];
    const int* eidx      = (const int*)d_in[2];
    const int* etype     = (const int*)d_in[3];
    const int* edir      = (const int*)d_in[4];
    const int* batch     = (const int*)d_in[5];
    const float* emb1    = (const float*)d_in[6];
    const float* emb2    = (const float*)d_in[7];
    const float* W       = (const float*)d_in[8];
    const float* ee1     = (const float*)d_in[10];
    const float* ee2     = (const float*)d_in[11];
    const float* gamma   = (const float*)d_in[12];
    const float* beta    = (const float*)d_in[13];
    const float* featW   = (const float*)d_in[14];
    const float* featb   = (const float*)d_in[15];
    const float* hW1     = (const float*)d_in[16];
    const float* hb1     = (const float*)d_in[17];
    const float* hW2     = (const float*)d_in[18];
    const float* hb2     = (const float*)d_in[19];

    int N = in_sizes[0];
    int E = in_sizes[2] / 2;
    const int* erow = eidx;
    const int* ecol = eidx + E;

    size_t off = 0;
    char* base = (char*)d_ws;
    auto carve = [&](size_t bytes) -> void* {
        void* p = base + off;
        off += (bytes + 255) & ~(size_t)255;
        return p;
    };
    u16*   P        = (u16*)  carve((size_t)N * SP * 2);
    u16*   Q        = (u16*)  carve((size_t)N * SP * 2);
    u16*   Wt       = (u16*)  carve((size_t)SP * SP * 2);
    u16*   comb     = (u16*)  carve((size_t)NCOMB * SP * 2);
    int*   c9map    = (int*)  carve((size_t)N * 4);
    int*   deg      = (int*)  carve((size_t)N * 4);
    int*   cursor   = (int*)  carve((size_t)N * 4);
    int*   indptr   = (int*)  carve((size_t)(N + 1) * 4);
    int*   packed   = (int*)  carve((size_t)E * 4);
    int*   bsum     = (int*)  carve(1024 * 4);
    int*   boff     = (int*)  carve(1024 * 4);
    float* colstats = (float*)carve((size_t)NREP * 2 * SP * 4);
    float* scale_id = (float*)carve(SP * 4);
    float* shift_id = (float*)carve(SP * 4);
    float* thr_id   = (float*)carve(SP * 4);
    float* scale_bn = (float*)carve(SP * 4);
    float* shift_bn = (float*)carve(SP * 4);
    float* thr_bn   = (float*)carve(SP * 4);
    float* srow     = (float*)carve(SP * 4);
    int*   gstart   = (int*)  carve((size_t)(NGRP + 1) * 4);
    float* hg       = (float*)carve((size_t)NGRP * EMB * 4);

    float* hf   = (float*)d_out;
    float* pred = (float*)d_out + (size_t)NGRP * FEAT;

    int eb = (E + 255) / 256;
    int NB = (N + 1023) / 1024;
    k_prep_n<<<(N + 255) / 256, 256, 0, stream>>>(atom_type, chir, c9map, deg, cursor, N);
    k_count<<<eb, 256, 0, stream>>>(ecol, deg, E);
    k_bsum<<<NB, 256, 0, stream>>>(deg, bsum, N);
    k_scanb<<<1, 128, 0, stream>>>(bsum, boff, NB);
    k_indptr<<<NB, 256, 0, stream>>>(deg, boff, indptr, N);
    k_fill<<<eb, 256, 0, stream>>>(erow, ecol, etype, edir, indptr, cursor, packed, E);

    k_comb<<<(NCOMB * 40 + 255) / 256, 256, 0, stream>>>(emb1, emb2, comb);
    k_ident<<<1, SP, 0, stream>>>(scale_id, shift_id, thr_id, colstats);

    const float* sc = scale_id;
    const float* sh = shift_id;
    const float* th = thr_id;
    dim3 ggrid(2, (N + MT - 1) / MT);   // x = n-tile, y = m-tile
    int ab = (N + 7) / 8;
    for (int l = 0; l < 5; l++) {
        k_wprep<<<SP, 320, 0, stream>>>(W + (size_t)l * EMB * EMB, sc, sh, Wt, srow);
        if (l == 0)
            k_gemm<<<ggrid, 256, 0, stream>>>(comb, Wt, th, srow, Q, N, c9map);
        else
            k_gemm<<<ggrid, 256, 0, stream>>>(P, Wt, th, srow, Q, N, nullptr);
        k_aggf<<<ab, 320, 0, stream>>>(Q, indptr, packed, ee1 + l * 5, ee2 + l * 3, P,
                                       colstats, N);
        k_finalize<<<1, SP, 0, stream>>>(colstats, gamma + l * EMB, beta + l * EMB,
                                         scale_bn, shift_bn, thr_bn, N);
        sc = scale_bn; sh = shift_bn; th = thr_bn;
    }

    k_bounds<<<(N + 1 + 255) / 256, 256, 0, stream>>>(batch, gstart, N);
    k_pool<<<NGRP / 8, 320, 0, stream>>>(P, scale_bn, shift_bn, gstart, hg);
    k_feat<<<NGRP / 16, 256, 0, stream>>>(hg, featW, featb, hf);
    k_head<<<NGRP / 8, 128, 0, stream>>>(hf, hW1, hb1, hW2, hb2, pred);
}

// Round 14
// 715.933 us; speedup vs baseline: 1.1448x; 1.1448x over previous
//
#include <hip/hip_runtime.h>
#include <math.h>

typedef unsigned short u16;
typedef unsigned int u32;
typedef short v8s __attribute__((ext_vector_type(8)));
typedef float v4f __attribute__((ext_vector_type(4)));

#define EMB 300
#define SP 320            // padded feature stride (bf16 elems)
#define NGRP 4096
#define FEAT 256
#define MT 128
#define NT 160
#define NCOMB 357         // 119 atom types x 3 chirality
#define NREP 32           // colstats replicas (atomic spread)

__device__ __forceinline__ u16 f2bf(float x) {
    u32 u = __float_as_uint(x);
    u += 0x7FFFu + ((u >> 16) & 1u);
    return (u16)(u >> 16);
}
__device__ __forceinline__ float bf2f(u16 h) {
    return __uint_as_float((u32)h << 16);
}
__device__ __forceinline__ void unpack8(uint4 w, float* o) {
    const u32* p = &w.x;
#pragma unroll
    for (int q = 0; q < 4; q++) {
        o[2 * q]     = __uint_as_float(p[q] << 16);
        o[2 * q + 1] = __uint_as_float(p[q] & 0xFFFF0000u);
    }
}
// clamp 8 packed bf16 against per-col bf16-exact thresholds (lossless repack)
__device__ __forceinline__ v8s clampA(uint4 w, float4 ta, float4 tb) {
    const u32* p = &w.x;
    float t[8] = {ta.x, ta.y, ta.z, ta.w, tb.x, tb.y, tb.z, tb.w};
    u32 o[4];
#pragma unroll
    for (int q = 0; q < 4; q++) {
        float lo = __uint_as_float(p[q] << 16);
        float hi = __uint_as_float(p[q] & 0xFFFF0000u);
        lo = fmaxf(lo, t[2 * q]);
        hi = fmaxf(hi, t[2 * q + 1]);
        o[q] = (__float_as_uint(lo) >> 16) | (__float_as_uint(hi) & 0xFFFF0000u);
    }
    uint4 r = make_uint4(o[0], o[1], o[2], o[3]);
    return *(v8s*)&r;
}
// async global->LDS DMA, 16B per lane (dest = wave-uniform base + lane*16)
__device__ __forceinline__ void dma16(const u16* g, u16* l) {
    __builtin_amdgcn_global_load_lds(
        (const __attribute__((address_space(1))) unsigned int*)g,
        (__attribute__((address_space(3))) unsigned int*)l, 16, 0, 0);
}

// ------------------- per-node prep: c9 map + zero deg/cursor ------------------
__global__ void k_prep_n(const int* __restrict__ at, const int* __restrict__ ch,
                         int* __restrict__ c9, int* __restrict__ deg,
                         int* __restrict__ cursor, int N) {
    int n = blockIdx.x * blockDim.x + threadIdx.x;
    if (n < N) {
        c9[n] = at[n] * 3 + ch[n];
        deg[n] = 0;
        cursor[n] = 0;
    }
}

// ------------------- CSR build -------------------
__global__ void k_count(const int* __restrict__ col, int* __restrict__ deg, int E) {
    int e = blockIdx.x * blockDim.x + threadIdx.x;
    if (e < E) atomicAdd(&deg[col[e]], 1);
}

__global__ __launch_bounds__(256) void k_bsum(const int* __restrict__ deg,
                                              int* __restrict__ bsum, int N) {
    int base = blockIdx.x * 1024 + threadIdx.x * 4;
    int s = 0;
    if (base + 3 < N) {
        int4 v = *(const int4*)(deg + base);
        s = v.x + v.y + v.z + v.w;
    } else {
        for (int j = 0; j < 4; j++) if (base + j < N) s += deg[base + j];
    }
    __shared__ int red[256];
    red[threadIdx.x] = s;
    __syncthreads();
    for (int off = 128; off > 0; off >>= 1) {
        if (threadIdx.x < off) red[threadIdx.x] += red[threadIdx.x + off];
        __syncthreads();
    }
    if (threadIdx.x == 0) bsum[blockIdx.x] = red[0];
}

__global__ __launch_bounds__(128) void k_scanb(const int* __restrict__ bsum,
                                               int* __restrict__ boff, int NB) {
    __shared__ int sh[128];
    int t = threadIdx.x;
    int v = (t < NB) ? bsum[t] : 0;
    sh[t] = v;
    __syncthreads();
    for (int off = 1; off < 128; off <<= 1) {
        int add = (t >= off) ? sh[t - off] : 0;
        __syncthreads();
        sh[t] += add;
        __syncthreads();
    }
    if (t < NB) boff[t] = sh[t] - v;
}

__global__ __launch_bounds__(256) void k_indptr(const int* __restrict__ deg,
                                                const int* __restrict__ boff,
                                                int* __restrict__ indptr, int N) {
    int b = blockIdx.x, t = threadIdx.x;
    int base = b * 1024 + t * 4;
    int v[4] = {0, 0, 0, 0};
    if (base + 3 < N) {
        int4 w = *(const int4*)(deg + base);
        v[0] = w.x; v[1] = w.y; v[2] = w.z; v[3] = w.w;
    } else {
        for (int j = 0; j < 4; j++) if (base + j < N) v[j] = deg[base + j];
    }
    int tsum = v[0] + v[1] + v[2] + v[3];
    __shared__ int sh[256];
    sh[t] = tsum;
    __syncthreads();
    for (int off = 1; off < 256; off <<= 1) {
        int add = (t >= off) ? sh[t - off] : 0;
        __syncthreads();
        sh[t] += add;
        __syncthreads();
    }
    int run = boff[b] + sh[t] - tsum;
    for (int j = 0; j < 4; j++) {
        run += v[j];
        if (base + j < N) indptr[base + j + 1] = run;
    }
    if (b == 0 && t == 0) indptr[0] = 0;
}

__global__ void k_fill(const int* __restrict__ row, const int* __restrict__ col,
                       const int* __restrict__ et, const int* __restrict__ ed,
                       const int* __restrict__ indptr, int* __restrict__ cursor,
                       int* __restrict__ packed, int E) {
    int e = blockIdx.x * blockDim.x + threadIdx.x;
    if (e >= E) return;
    int c = col[e];
    int pos = indptr[c] + atomicAdd(&cursor[c], 1);
    packed[pos] = row[e] | ((et[e] * 3 + ed[e]) << 17);
}

// ------------------- comb table: comb[at*3+ch] = bf16(e1[at] + e2[ch]) --------
__global__ void k_comb(const float* __restrict__ e1, const float* __restrict__ e2,
                       u16* __restrict__ comb) {
    int idx = blockIdx.x * blockDim.x + threadIdx.x;
    if (idx >= NCOMB * 40) return;
    int row = idx / 40, f = idx % 40;
    int at = row / 3, ch = row % 3;
    u32 o[4];
#pragma unroll
    for (int q = 0; q < 4; q++) {
        int c0 = f * 8 + q * 2;
        float x0 = 0.f, x1 = 0.f;
        if (c0 < EMB)     x0 = e1[(size_t)at * EMB + c0] + e2[(size_t)ch * EMB + c0];
        if (c0 + 1 < EMB) x1 = e1[(size_t)at * EMB + c0 + 1] + e2[(size_t)ch * EMB + c0 + 1];
        o[q] = (u32)f2bf(x0) | ((u32)f2bf(x1) << 16);
    }
    *(uint4*)(comb + (size_t)row * SP + f * 8) = make_uint4(o[0], o[1], o[2], o[3]);
}

// ------------------- merged W prep: Wt + srow (one W-column read) -------------
__global__ __launch_bounds__(320) void k_wprep(
    const float* __restrict__ Wl, const float* __restrict__ sc,
    const float* __restrict__ sh, u16* __restrict__ Wt, float* __restrict__ srow) {
    __shared__ float wred[5];
    int n = blockIdx.x;
    int k = threadIdx.x;
    float w = 0.f;
    if (n < EMB && k < EMB) w = Wl[(size_t)k * EMB + n];
    Wt[(size_t)n * SP + k] = f2bf(w * sc[k]);
    float s = (k < EMB) ? sh[k] * w : 0.f;
#pragma unroll
    for (int o2 = 32; o2 > 0; o2 >>= 1) s += __shfl_down(s, o2);
    if ((k & 63) == 0) wred[k >> 6] = s;
    __syncthreads();
    if (k == 0) {
        float t = wred[0] + wred[1] + wred[2] + wred[3] + wred[4];
        srow[n] = (n < EMB) ? t : 0.f;
    }
}

// ------------------- identity (layer 0) / BN-finalize -------------------------
// k_ident zeroes all NREP colstats replicas.
__global__ void k_ident(float* __restrict__ sc, float* __restrict__ sh,
                        float* __restrict__ thr, float* __restrict__ colstats) {
    int c = threadIdx.x;
    if (c < SP) {
        sc[c] = (c < EMB) ? 1.f : 0.f;
        sh[c] = 0.f;
        thr[c] = -__builtin_inff();
        for (int r = 0; r < NREP; r++) {
            colstats[r * 2 * SP + c] = 0.f;
            colstats[r * 2 * SP + SP + c] = 0.f;
        }
    }
}

// sums the NREP replicas, computes BN scale/shift/threshold, re-zeros replicas.
__global__ void k_finalize(float* __restrict__ cs,
                           const float* __restrict__ gamma, const float* __restrict__ beta,
                           float* __restrict__ sc, float* __restrict__ sh,
                           float* __restrict__ thr, int N) {
    int c = threadIdx.x;
    if (c >= SP) return;
    float s1 = 0.f, s2 = 0.f;
    for (int r = 0; r < NREP; r++) {
        s1 += cs[r * 2 * SP + c];
        s2 += cs[r * 2 * SP + SP + c];
        cs[r * 2 * SP + c] = 0.f;
        cs[r * 2 * SP + SP + c] = 0.f;
    }
    if (c < EMB) {
        float inv = 1.f / (float)N;
        float mean = s1 * inv;
        float var = s2 * inv - mean * mean;
        float rstd = rsqrtf(fmaxf(var, 0.f) + 1e-5f);
        float s = gamma[c] * rstd;
        float b = beta[c] - mean * s;
        sc[c] = s;
        sh[c] = b;
        thr[c] = bf2f(f2bf(-b / s));
    } else {
        sc[c] = 0.f; sh[c] = 0.f; thr[c] = -__builtin_inff();
    }
}

// ------------------- GEMM: Q = max(A[rowmap], thr) @ Wt + srow  ---------------
// r12-proven DMA double-buffered staging for BOTH A and B (BK=32), plus the
// r13-proven two-pass 64-row epilogue. LDS = max(36.9 KB staging, 21.5 KB
// overlay) = 36.9 KB -> 4 blocks/CU (vs 3 at 43 KB).
__global__ __launch_bounds__(256) void k_gemm(
    const u16* __restrict__ A, const u16* __restrict__ Wt,
    const float* __restrict__ thr, const float* __restrict__ srow,
    u16* __restrict__ C, int M, const int* __restrict__ rowmap) {
    __shared__ __align__(16) u16 sm[18432];   // As 2x4096 | Bs 2x5120 ; epi 64x168 overlay

    int m0 = blockIdx.y * MT;
    int n0 = blockIdx.x * NT;
    int tid = threadIdx.x;
    int wave = tid >> 6, lane = tid & 63;
    int wm = wave >> 1, wn = wave & 1;
    int lm = lane & 15, quad = lane >> 4;

    int ar0 = min(m0 + (tid >> 2), M - 1);
    int ar1 = min(m0 + 64 + (tid >> 2), M - 1);
    if (rowmap) { ar0 = rowmap[ar0]; ar1 = rowmap[ar1]; }
    const u16* ag0 = A + (size_t)ar0 * SP + (tid & 3) * 8;
    const u16* ag1 = A + (size_t)ar1 * SP + (tid & 3) * 8;
    const u16* bg0 = Wt + (size_t)(n0 + (tid >> 2)) * SP + (tid & 3) * 8;
    const u16* bg1 = Wt + (size_t)(n0 + 64 + (tid >> 2)) * SP + (tid & 3) * 8;
    const u16* bg2 = Wt + (size_t)(n0 + 128 + (tid >> 2)) * SP + (tid & 3) * 8;

    const float* tp = thr + quad * 8;

    v4f acc[4][5];
#pragma unroll
    for (int nf = 0; nf < 5; nf++) {
        float sv = srow[n0 + wn * 80 + nf * 16 + lm];
#pragma unroll
        for (int mf = 0; mf < 4; mf++)
            acc[mf][nf] = (v4f){sv, sv, sv, sv};
    }

    auto issue = [&](int d, int kt) {
        int ko = kt * 32;
        u16* ad = sm + d * 4096;
        u16* bd = sm + 8192 + d * 5120;
        dma16(ag0 + ko, ad + tid * 8);
        dma16(ag1 + ko, ad + (256 + tid) * 8);
        dma16(bg0 + ko, bd + tid * 8);
        dma16(bg1 + ko, bd + (256 + tid) * 8);
        if (tid < 128) dma16(bg2 + ko, bd + (512 + tid) * 8);
    };

    issue(0, 0);
    for (int kt = 0; kt < SP / 32; kt++) {
        __syncthreads();                      // drains this ktile's DMA
        if (kt + 1 < SP / 32) issue((kt + 1) & 1, kt + 1);
        const u16* as = sm + (kt & 1) * 4096;
        const u16* bs = sm + 8192 + (kt & 1) * 5120;
        float4 ta = *(const float4*)(tp + kt * 32);
        float4 tb = *(const float4*)(tp + kt * 32 + 4);
        v8s b[5], a[4];
#pragma unroll
        for (int nf = 0; nf < 5; nf++)
            b[nf] = *(const v8s*)(bs + (wn * 80 + nf * 16 + lm) * 32 + quad * 8);
#pragma unroll
        for (int mf = 0; mf < 4; mf++) {
            uint4 w = *(const uint4*)(as + (wm * 64 + mf * 16 + lm) * 32 + quad * 8);
            a[mf] = clampA(w, ta, tb);
        }
#pragma unroll
        for (int nf = 0; nf < 5; nf++)
#pragma unroll
            for (int mf = 0; mf < 4; mf++)
                acc[mf][nf] = __builtin_amdgcn_mfma_f32_16x16x32_bf16(a[mf], b[nf], acc[mf][nf], 0, 0, 0);
    }

    __syncthreads();                          // staging reads done -> overlay
    // epilogue: two 64-row passes through the 64x168 overlay (r13-proven)
#pragma unroll
    for (int p = 0; p < 2; p++) {
#pragma unroll
        for (int mf2 = 0; mf2 < 2; mf2++) {
            int mf = p * 2 + mf2;
#pragma unroll
            for (int nf = 0; nf < 5; nf++)
#pragma unroll
                for (int r = 0; r < 4; r++)
                    sm[(wm * 32 + mf2 * 16 + quad * 4 + r) * 168 + wn * 80 + nf * 16 + lm] =
                        f2bf(acc[mf][nf][r]);
        }
        __syncthreads();
#pragma unroll
        for (int i = 0; i < 5; i++) {
            int slot = tid + i * 256;         // 1280 slots = 64 rows x 20 cgroups
            int lr = slot / 20, cg = slot % 20;
            int grow = m0 + (lr >> 5) * 64 + p * 32 + (lr & 31);
            if (grow < M)
                *(uint4*)(C + (size_t)grow * SP + n0 + cg * 8) =
                    *(const uint4*)(sm + lr * 168 + cg * 8);
        }
        __syncthreads();
    }
}

// ------------------- aggregate + fused BN stats, flat one-node-per-slot -------
__global__ __launch_bounds__(320) void k_aggf(
    const u16* __restrict__ Q, const int* __restrict__ indptr,
    const int* __restrict__ packed, const float* __restrict__ e1,
    const float* __restrict__ e2, u16* __restrict__ P,
    float* __restrict__ colstats, int N) {
    __shared__ float tab[15];
    __shared__ float part[8][328];
    int tid = threadIdx.x;
    if (tid < 15) tab[tid] = e1[tid / 3] + e2[tid % 3];
    __syncthreads();
    int f = tid % 40;
    int slot = tid / 40;
    int n = blockIdx.x * 8 + slot;

    float psum[8] = {0, 0, 0, 0, 0, 0, 0, 0};
    float psq[8]  = {0, 0, 0, 0, 0, 0, 0, 0};

    if (n < N) {
        float acc[8];
        unpack8(*(const uint4*)(Q + (size_t)n * SP + f * 8), acc);
        float s = tab[12];                  // self loop: et=4, ed=0 -> code 12
        int i = indptr[n], e = indptr[n + 1];
        int pk = (i < e) ? packed[i] : 0;
        while (i < e) {
            uint4 g = *(const uint4*)(Q + (size_t)(pk & 0x1FFFF) * SP + f * 8);
            int nx = i + 1;
            int pkn = (nx < e) ? packed[nx] : 0;
            float t[8];
            unpack8(g, t);
#pragma unroll
            for (int q = 0; q < 8; q++) acc[q] += t[q];
            s += tab[pk >> 17];
            i = nx; pk = pkn;
        }
        u32 o[4];
#pragma unroll
        for (int q = 0; q < 4; q++) {
            float r0 = acc[2 * q] + s;
            float r1 = acc[2 * q + 1] + s;
            psum[2 * q] = r0;      psum[2 * q + 1] = r1;
            psq[2 * q]  = r0 * r0; psq[2 * q + 1]  = r1 * r1;
            o[q] = (u32)f2bf(r0) | ((u32)f2bf(r1) << 16);
        }
        *(uint4*)(P + (size_t)n * SP + f * 8) = make_uint4(o[0], o[1], o[2], o[3]);
    }

    int rep = (blockIdx.x & (NREP - 1)) * 2 * SP;
#pragma unroll
    for (int j = 0; j < 8; j++) part[slot][f * 8 + j] = psum[j];
    __syncthreads();
    {
        float s = 0.f;
#pragma unroll
        for (int k = 0; k < 8; k++) s += part[k][tid];
        atomicAdd(&colstats[rep + tid], s);
    }
    __syncthreads();
#pragma unroll
    for (int j = 0; j < 8; j++) part[slot][f * 8 + j] = psq[j];
    __syncthreads();
    {
        float s = 0.f;
#pragma unroll
        for (int k = 0; k < 8; k++) s += part[k][tid];
        atomicAdd(&colstats[rep + SP + tid], s);
    }
}

// ------------------- group boundaries from sorted batch -------------------
__global__ void k_bounds(const int* __restrict__ batch, int* __restrict__ gstart, int N) {
    int n = blockIdx.x * blockDim.x + threadIdx.x;
    if (n > N) return;
    int bcur = (n < N) ? batch[n] : NGRP;
    int bprev = (n > 0) ? batch[n - 1] : -1;
    for (int g = bprev + 1; g <= bcur; g++) gstart[g] = n;
}

// ------------------- pool (BN layer4 fused, no relu), 8 groups/block ----------
__global__ __launch_bounds__(320) void k_pool(
    const u16* __restrict__ P, const float* __restrict__ sc,
    const float* __restrict__ sh, const int* __restrict__ gstart,
    float* __restrict__ hg) {
    int tid = threadIdx.x;
    int g = blockIdx.x * 8 + tid / 40;
    int f = tid % 40;
    int r0 = gstart[g], r1 = gstart[g + 1];
    int cnt = r1 - r0;
    float acc[8] = {0, 0, 0, 0, 0, 0, 0, 0};
    for (int r = r0; r < r1; r++) {
        float t[8];
        unpack8(*(const uint4*)(P + (size_t)r * SP + f * 8), t);
#pragma unroll
        for (int j = 0; j < 8; j++) acc[j] += t[j];
    }
    float inv = 1.f / (float)max(cnt, 1);
#pragma unroll
    for (int j = 0; j < 8; j++) {
        int c = f * 8 + j;
        if (c < EMB)
            hg[(size_t)g * EMB + c] = (acc[j] * sc[c] + (float)cnt * sh[c]) * inv;
    }
}

// ------------------- hf = hg @ feat_W + feat_b -------------------
__global__ __launch_bounds__(256) void k_feat(const float* __restrict__ hg,
                                              const float* __restrict__ fW,
                                              const float* __restrict__ fb,
                                              float* __restrict__ hf) {
    __shared__ float hgs[16 * EMB];
    int g0 = blockIdx.x * 16;
    int tid = threadIdx.x;
    for (int i = tid; i < 16 * EMB; i += 256) {
        int gi = i / EMB, c = i % EMB;
        hgs[i] = hg[(size_t)(g0 + gi) * EMB + c];
    }
    __syncthreads();
    float acc[16];
    float fbv = fb[tid];
#pragma unroll
    for (int gi = 0; gi < 16; gi++) acc[gi] = fbv;
    for (int k = 0; k < EMB; k++) {
        float w = fW[(size_t)k * FEAT + tid];
#pragma unroll
        for (int gi = 0; gi < 16; gi++) acc[gi] += hgs[gi * EMB + k] * w;
    }
#pragma unroll
    for (int gi = 0; gi < 16; gi++) hf[(size_t)(g0 + gi) * FEAT + tid] = acc[gi];
}

// ------------------- head: pred = softplus(hf@W1+b1)@W2+b2 -------------------
__global__ __launch_bounds__(128) void k_head(const float* __restrict__ hf,
                                              const float* __restrict__ W1,
                                              const float* __restrict__ b1,
                                              const float* __restrict__ W2,
                                              const float* __restrict__ b2,
                                              float* __restrict__ pred) {
    __shared__ float hfs[8 * FEAT];
    __shared__ float sred[2][8][2];
    int g0 = blockIdx.x * 8;
    int tid = threadIdx.x;
    for (int i = tid; i < 8 * FEAT; i += 128) {
        int gi = i >> 8, k = i & 255;
        hfs[i] = hf[(size_t)(g0 + gi) * FEAT + k];
    }
    __syncthreads();
    float acc[8];
    float b1v = b1[tid];
#pragma unroll
    for (int gi = 0; gi < 8; gi++) acc[gi] = b1v;
    for (int k = 0; k < FEAT; k++) {
        float w = W1[(size_t)k * 128 + tid];
#pragma unroll
        for (int gi = 0; gi < 8; gi++) acc[gi] += hfs[gi * FEAT + k] * w;
    }
    float w20 = W2[tid * 2], w21 = W2[tid * 2 + 1];
    int wv = tid >> 6;
#pragma unroll
    for (int gi = 0; gi < 8; gi++) {
        float x = acc[gi];
        float t = fmaxf(x, 0.f) + log1pf(expf(-fabsf(x)));
        float p0 = t * w20, p1 = t * w21;
#pragma unroll
        for (int off = 32; off > 0; off >>= 1) {
            p0 += __shfl_down(p0, off);
            p1 += __shfl_down(p1, off);
        }
        if ((tid & 63) == 0) { sred[wv][gi][0] = p0; sred[wv][gi][1] = p1; }
    }
    __syncthreads();
    if (tid < 16) {
        int gi = tid >> 1, o = tid & 1;
        pred[(size_t)(g0 + gi) * 2 + o] = sred[0][gi][o] + sred[1][gi][o] + b2[o];
    }
}

// ------------------- launch -------------------
extern "C" void kernel_launch(void* const* d_in, const int* in_sizes, int n_in,
                              void* d_out, int out_size, void* d_ws, size_t ws_size,
                              hipStream_t stream) {
    const int* atom_type = (const int*)d_in[0];
    const int* chir      = (const int*)d_in[1];
    const int* eidx      = (const int*)d_in[2];
    const int* etype     = (const int*)d_in[3];
    const int* edir      = (const int*)d_in[4];
    const int* batch     = (const int*)d_in[5];
    const float* emb1    = (const float*)d_in[6];
    const float* emb2    = (const float*)d_in[7];
    const float* W       = (const float*)d_in[8];
    const float* ee1     = (const float*)d_in[10];
    const float* ee2     = (const float*)d_in[11];
    const float* gamma   = (const float*)d_in[12];
    const float* beta    = (const float*)d_in[13];
    const float* featW   = (const float*)d_in[14];
    const float* featb   = (const float*)d_in[15];
    const float* hW1     = (const float*)d_in[16];
    const float* hb1     = (const float*)d_in[17];
    const float* hW2     = (const float*)d_in[18];
    const float* hb2     = (const float*)d_in[19];

    int N = in_sizes[0];
    int E = in_sizes[2] / 2;
    const int* erow = eidx;
    const int* ecol = eidx + E;

    size_t off = 0;
    char* base = (char*)d_ws;
    auto carve = [&](size_t bytes) -> void* {
        void* p = base + off;
        off += (bytes + 255) & ~(size_t)255;
        return p;
    };
    u16*   P        = (u16*)  carve((size_t)N * SP * 2);
    u16*   Q        = (u16*)  carve((size_t)N * SP * 2);
    u16*   Wt       = (u16*)  carve((size_t)SP * SP * 2);
    u16*   comb     = (u16*)  carve((size_t)NCOMB * SP * 2);
    int*   c9map    = (int*)  carve((size_t)N * 4);
    int*   deg      = (int*)  carve((size_t)N * 4);
    int*   cursor   = (int*)  carve((size_t)N * 4);
    int*   indptr   = (int*)  carve((size_t)(N + 1) * 4);
    int*   packed   = (int*)  carve((size_t)E * 4);
    int*   bsum     = (int*)  carve(1024 * 4);
    int*   boff     = (int*)  carve(1024 * 4);
    float* colstats = (float*)carve((size_t)NREP * 2 * SP * 4);
    float* scale_id = (float*)carve(SP * 4);
    float* shift_id = (float*)carve(SP * 4);
    float* thr_id   = (float*)carve(SP * 4);
    float* scale_bn = (float*)carve(SP * 4);
    float* shift_bn = (float*)carve(SP * 4);
    float* thr_bn   = (float*)carve(SP * 4);
    float* srow     = (float*)carve(SP * 4);
    int*   gstart   = (int*)  carve((size_t)(NGRP + 1) * 4);
    float* hg       = (float*)carve((size_t)NGRP * EMB * 4);

    float* hf   = (float*)d_out;
    float* pred = (float*)d_out + (size_t)NGRP * FEAT;

    int eb = (E + 255) / 256;
    int NB = (N + 1023) / 1024;
    k_prep_n<<<(N + 255) / 256, 256, 0, stream>>>(atom_type, chir, c9map, deg, cursor, N);
    k_count<<<eb, 256, 0, stream>>>(ecol, deg, E);
    k_bsum<<<NB, 256, 0, stream>>>(deg, bsum, N);
    k_scanb<<<1, 128, 0, stream>>>(bsum, boff, NB);
    k_indptr<<<NB, 256, 0, stream>>>(deg, boff, indptr, N);
    k_fill<<<eb, 256, 0, stream>>>(erow, ecol, etype, edir, indptr, cursor, packed, E);

    k_comb<<<(NCOMB * 40 + 255) / 256, 256, 0, stream>>>(emb1, emb2, comb);
    k_ident<<<1, SP, 0, stream>>>(scale_id, shift_id, thr_id, colstats);

    const float* sc = scale_id;
    const float* sh = shift_id;
    const float* th = thr_id;
    dim3 ggrid(2, (N + MT - 1) / MT);   // x = n-tile, y = m-tile
    int ab = (N + 7) / 8;
    for (int l = 0; l < 5; l++) {
        k_wprep<<<SP, 320, 0, stream>>>(W + (size_t)l * EMB * EMB, sc, sh, Wt, srow);
        if (l == 0)
            k_gemm<<<ggrid, 256, 0, stream>>>(comb, Wt, th, srow, Q, N, c9map);
        else
            k_gemm<<<ggrid, 256, 0, stream>>>(P, Wt, th, srow, Q, N, nullptr);
        k_aggf<<<ab, 320, 0, stream>>>(Q, indptr, packed, ee1 + l * 5, ee2 + l * 3, P,
                                       colstats, N);
        k_finalize<<<1, SP, 0, stream>>>(colstats, gamma + l * EMB, beta + l * EMB,
                                         scale_bn, shift_bn, thr_bn, N);
        sc = scale_bn; sh = shift_bn; th = thr_bn;
    }

    k_bounds<<<(N + 1 + 255) / 256, 256, 0, stream>>>(batch, gstart, N);
    k_pool<<<NGRP / 8, 320, 0, stream>>>(P, scale_bn, shift_bn, gstart, hg);
    k_feat<<<NGRP / 16, 256, 0, stream>>>(hg, featW, featb, hf);
    k_head<<<NGRP / 8, 128, 0, stream>>>(hf, hW1, hb1, hW2, hb2, pred);
}

// Round 15
// 703.090 us; speedup vs baseline: 1.1657x; 1.0183x over previous
//
#include <hip/hip_runtime.h>
#include <math.h>

typedef unsigned short u16;
typedef unsigned int u32;
typedef short v8s __attribute__((ext_vector_type(8)));
typedef float v4f __attribute__((ext_vector_type(4)));

#define EMB 300
#define SP 320            // padded feature stride (bf16 elems)
#define NGRP 4096
#define FEAT 256
#define MT 128
#define NT 160
#define NCOMB 357         // 119 atom types x 3 chirality
#define NREP 32           // colstats replicas (atomic spread)
#define CSB (NREP * 2 * SP)   // floats per colstats bank

__device__ __forceinline__ u16 f2bf(float x) {
    u32 u = __float_as_uint(x);
    u += 0x7FFFu + ((u >> 16) & 1u);
    return (u16)(u >> 16);
}
__device__ __forceinline__ float bf2f(u16 h) {
    return __uint_as_float((u32)h << 16);
}
__device__ __forceinline__ void unpack8(uint4 w, float* o) {
    const u32* p = &w.x;
#pragma unroll
    for (int q = 0; q < 4; q++) {
        o[2 * q]     = __uint_as_float(p[q] << 16);
        o[2 * q + 1] = __uint_as_float(p[q] & 0xFFFF0000u);
    }
}
// clamp 8 packed bf16 against per-col bf16-exact thresholds (lossless repack)
__device__ __forceinline__ v8s clampA(uint4 w, float4 ta, float4 tb) {
    const u32* p = &w.x;
    float t[8] = {ta.x, ta.y, ta.z, ta.w, tb.x, tb.y, tb.z, tb.w};
    u32 o[4];
#pragma unroll
    for (int q = 0; q < 4; q++) {
        float lo = __uint_as_float(p[q] << 16);
        float hi = __uint_as_float(p[q] & 0xFFFF0000u);
        lo = fmaxf(lo, t[2 * q]);
        hi = fmaxf(hi, t[2 * q + 1]);
        o[q] = (__float_as_uint(lo) >> 16) | (__float_as_uint(hi) & 0xFFFF0000u);
    }
    uint4 r = make_uint4(o[0], o[1], o[2], o[3]);
    return *(v8s*)&r;
}
// async global->LDS DMA, 16B per lane (dest = wave-uniform base + lane*16)
__device__ __forceinline__ void dma16(const u16* g, u16* l) {
    __builtin_amdgcn_global_load_lds(
        (const __attribute__((address_space(1))) unsigned int*)g,
        (__attribute__((address_space(3))) unsigned int*)l, 16, 0, 0);
}

// ---------- per-node prep: c9 map + zero deg/cursor + zero colstats bank 0 ----
__global__ void k_prep_n(const int* __restrict__ at, const int* __restrict__ ch,
                         int* __restrict__ c9, int* __restrict__ deg,
                         int* __restrict__ cursor, float* __restrict__ cs0, int N) {
    int n = blockIdx.x * blockDim.x + threadIdx.x;
    if (n < N) {
        c9[n] = at[n] * 3 + ch[n];
        deg[n] = 0;
        cursor[n] = 0;
    }
    if (n < CSB) cs0[n] = 0.f;
}

// ------------------- CSR build -------------------
__global__ void k_count(const int* __restrict__ col, int* __restrict__ deg, int E) {
    int e = blockIdx.x * blockDim.x + threadIdx.x;
    if (e < E) atomicAdd(&deg[col[e]], 1);
}

__global__ __launch_bounds__(256) void k_bsum(const int* __restrict__ deg,
                                              int* __restrict__ bsum, int N) {
    int base = blockIdx.x * 1024 + threadIdx.x * 4;
    int s = 0;
    if (base + 3 < N) {
        int4 v = *(const int4*)(deg + base);
        s = v.x + v.y + v.z + v.w;
    } else {
        for (int j = 0; j < 4; j++) if (base + j < N) s += deg[base + j];
    }
    __shared__ int red[256];
    red[threadIdx.x] = s;
    __syncthreads();
    for (int off = 128; off > 0; off >>= 1) {
        if (threadIdx.x < off) red[threadIdx.x] += red[threadIdx.x + off];
        __syncthreads();
    }
    if (threadIdx.x == 0) bsum[blockIdx.x] = red[0];
}

__global__ __launch_bounds__(128) void k_scanb(const int* __restrict__ bsum,
                                               int* __restrict__ boff, int NB) {
    __shared__ int sh[128];
    int t = threadIdx.x;
    int v = (t < NB) ? bsum[t] : 0;
    sh[t] = v;
    __syncthreads();
    for (int off = 1; off < 128; off <<= 1) {
        int add = (t >= off) ? sh[t - off] : 0;
        __syncthreads();
        sh[t] += add;
        __syncthreads();
    }
    if (t < NB) boff[t] = sh[t] - v;
}

__global__ __launch_bounds__(256) void k_indptr(const int* __restrict__ deg,
                                                const int* __restrict__ boff,
                                                int* __restrict__ indptr, int N) {
    int b = blockIdx.x, t = threadIdx.x;
    int base = b * 1024 + t * 4;
    int v[4] = {0, 0, 0, 0};
    if (base + 3 < N) {
        int4 w = *(const int4*)(deg + base);
        v[0] = w.x; v[1] = w.y; v[2] = w.z; v[3] = w.w;
    } else {
        for (int j = 0; j < 4; j++) if (base + j < N) v[j] = deg[base + j];
    }
    int tsum = v[0] + v[1] + v[2] + v[3];
    __shared__ int sh[256];
    sh[t] = tsum;
    __syncthreads();
    for (int off = 1; off < 256; off <<= 1) {
        int add = (t >= off) ? sh[t - off] : 0;
        __syncthreads();
        sh[t] += add;
        __syncthreads();
    }
    int run = boff[b] + sh[t] - tsum;
    for (int j = 0; j < 4; j++) {
        run += v[j];
        if (base + j < N) indptr[base + j + 1] = run;
    }
    if (b == 0 && t == 0) indptr[0] = 0;
}

__global__ void k_fill(const int* __restrict__ row, const int* __restrict__ col,
                       const int* __restrict__ et, const int* __restrict__ ed,
                       const int* __restrict__ indptr, int* __restrict__ cursor,
                       int* __restrict__ packed, int E) {
    int e = blockIdx.x * blockDim.x + threadIdx.x;
    if (e >= E) return;
    int c = col[e];
    int pos = indptr[c] + atomicAdd(&cursor[c], 1);
    packed[pos] = row[e] | ((et[e] * 3 + ed[e]) << 17);
}

// ------------------- comb table: comb[at*3+ch] = bf16(e1[at] + e2[ch]) --------
__global__ void k_comb(const float* __restrict__ e1, const float* __restrict__ e2,
                       u16* __restrict__ comb) {
    int idx = blockIdx.x * blockDim.x + threadIdx.x;
    if (idx >= NCOMB * 40) return;
    int row = idx / 40, f = idx % 40;
    int at = row / 3, ch = row % 3;
    u32 o[4];
#pragma unroll
    for (int q = 0; q < 4; q++) {
        int c0 = f * 8 + q * 2;
        float x0 = 0.f, x1 = 0.f;
        if (c0 < EMB)     x0 = e1[(size_t)at * EMB + c0] + e2[(size_t)ch * EMB + c0];
        if (c0 + 1 < EMB) x1 = e1[(size_t)at * EMB + c0 + 1] + e2[(size_t)ch * EMB + c0 + 1];
        o[q] = (u32)f2bf(x0) | ((u32)f2bf(x1) << 16);
    }
    *(uint4*)(comb + (size_t)row * SP + f * 8) = make_uint4(o[0], o[1], o[2], o[3]);
}

// ---- fused W prep: BN-finalize (from replica sums) + Wt + srow + thr ---------
// Each block redundantly reduces the colstats bank (L2-resident, <1us total).
// ident=1 (layer 0): sc=1, sh=0, thr=-inf. Block n==0 writes thr[] for k_gemm.
__global__ __launch_bounds__(320) void k_wprep(
    const float* __restrict__ Wl, const float* __restrict__ cs,
    const float* __restrict__ gamma, const float* __restrict__ beta,
    int ident, int N, u16* __restrict__ Wt, float* __restrict__ srow,
    float* __restrict__ thr) {
    __shared__ float wred[5];
    int n = blockIdx.x;
    int k = threadIdx.x;
    float scv, shv, thv;
    if (ident) {
        scv = (k < EMB) ? 1.f : 0.f;
        shv = 0.f;
        thv = -__builtin_inff();
    } else if (k < EMB) {
        float s1 = 0.f, s2 = 0.f;
        for (int r = 0; r < NREP; r++) {
            s1 += cs[r * 2 * SP + k];
            s2 += cs[r * 2 * SP + SP + k];
        }
        float inv = 1.f / (float)N;
        float mean = s1 * inv;
        float var = s2 * inv - mean * mean;
        float rstd = rsqrtf(fmaxf(var, 0.f) + 1e-5f);
        scv = gamma[k] * rstd;
        shv = beta[k] - mean * scv;
        thv = bf2f(f2bf(-shv / scv));
    } else {
        scv = 0.f; shv = 0.f; thv = -__builtin_inff();
    }
    if (n == 0) thr[k] = thv;

    float w = 0.f;
    if (n < EMB && k < EMB) w = Wl[(size_t)k * EMB + n];
    Wt[(size_t)n * SP + k] = f2bf(w * scv);
    float s = (k < EMB) ? shv * w : 0.f;
#pragma unroll
    for (int o2 = 32; o2 > 0; o2 >>= 1) s += __shfl_down(s, o2);
    if ((k & 63) == 0) wred[k >> 6] = s;
    __syncthreads();
    if (k == 0) {
        float t = wred[0] + wred[1] + wred[2] + wred[3] + wred[4];
        srow[n] = (n < EMB) ? t : 0.f;
    }
}

// --------- final BN params (layer 4) for the pool, from colstats bank ---------
__global__ void k_finalize(const float* __restrict__ cs,
                           const float* __restrict__ gamma, const float* __restrict__ beta,
                           float* __restrict__ sc, float* __restrict__ sh, int N) {
    int c = threadIdx.x;
    if (c >= SP) return;
    float s1 = 0.f, s2 = 0.f;
    for (int r = 0; r < NREP; r++) {
        s1 += cs[r * 2 * SP + c];
        s2 += cs[r * 2 * SP + SP + c];
    }
    if (c < EMB) {
        float inv = 1.f / (float)N;
        float mean = s1 * inv;
        float var = s2 * inv - mean * mean;
        float rstd = rsqrtf(fmaxf(var, 0.f) + 1e-5f);
        float s = gamma[c] * rstd;
        sc[c] = s;
        sh[c] = beta[c] - mean * s;
    } else {
        sc[c] = 0.f; sh[c] = 0.f;
    }
}

// ------------------- GEMM: Q = max(A[rowmap], thr) @ Wt + srow  ---------------
// r12/r14-proven DMA double-buffered staging (BK=32) + two-pass epilogue.
// Block (0,0) also zeros the *other* colstats bank for the next layer's aggf.
__global__ __launch_bounds__(256) void k_gemm(
    const u16* __restrict__ A, const u16* __restrict__ Wt,
    const float* __restrict__ thr, const float* __restrict__ srow,
    u16* __restrict__ C, int M, const int* __restrict__ rowmap,
    float* __restrict__ zbank) {
    __shared__ __align__(16) u16 sm[18432];   // As 2x4096 | Bs 2x5120 ; epi 64x168

    int m0 = blockIdx.y * MT;
    int n0 = blockIdx.x * NT;
    int tid = threadIdx.x;
    int wave = tid >> 6, lane = tid & 63;
    int wm = wave >> 1, wn = wave & 1;
    int lm = lane & 15, quad = lane >> 4;

    if (blockIdx.x == 0 && blockIdx.y == 0)
        for (int i = tid; i < CSB; i += 256) zbank[i] = 0.f;

    int ar0 = min(m0 + (tid >> 2), M - 1);
    int ar1 = min(m0 + 64 + (tid >> 2), M - 1);
    if (rowmap) { ar0 = rowmap[ar0]; ar1 = rowmap[ar1]; }
    const u16* ag0 = A + (size_t)ar0 * SP + (tid & 3) * 8;
    const u16* ag1 = A + (size_t)ar1 * SP + (tid & 3) * 8;
    const u16* bg0 = Wt + (size_t)(n0 + (tid >> 2)) * SP + (tid & 3) * 8;
    const u16* bg1 = Wt + (size_t)(n0 + 64 + (tid >> 2)) * SP + (tid & 3) * 8;
    const u16* bg2 = Wt + (size_t)(n0 + 128 + (tid >> 2)) * SP + (tid & 3) * 8;

    const float* tp = thr + quad * 8;

    v4f acc[4][5];
#pragma unroll
    for (int nf = 0; nf < 5; nf++) {
        float sv = srow[n0 + wn * 80 + nf * 16 + lm];
#pragma unroll
        for (int mf = 0; mf < 4; mf++)
            acc[mf][nf] = (v4f){sv, sv, sv, sv};
    }

    auto issue = [&](int d, int kt) {
        int ko = kt * 32;
        u16* ad = sm + d * 4096;
        u16* bd = sm + 8192 + d * 5120;
        dma16(ag0 + ko, ad + tid * 8);
        dma16(ag1 + ko, ad + (256 + tid) * 8);
        dma16(bg0 + ko, bd + tid * 8);
        dma16(bg1 + ko, bd + (256 + tid) * 8);
        if (tid < 128) dma16(bg2 + ko, bd + (512 + tid) * 8);
    };

    issue(0, 0);
    for (int kt = 0; kt < SP / 32; kt++) {
        __syncthreads();                      // drains this ktile's DMA
        if (kt + 1 < SP / 32) issue((kt + 1) & 1, kt + 1);
        const u16* as = sm + (kt & 1) * 4096;
        const u16* bs = sm + 8192 + (kt & 1) * 5120;
        float4 ta = *(const float4*)(tp + kt * 32);
        float4 tb = *(const float4*)(tp + kt * 32 + 4);
        v8s b[5], a[4];
#pragma unroll
        for (int nf = 0; nf < 5; nf++)
            b[nf] = *(const v8s*)(bs + (wn * 80 + nf * 16 + lm) * 32 + quad * 8);
#pragma unroll
        for (int mf = 0; mf < 4; mf++) {
            uint4 w = *(const uint4*)(as + (wm * 64 + mf * 16 + lm) * 32 + quad * 8);
            a[mf] = clampA(w, ta, tb);
        }
#pragma unroll
        for (int nf = 0; nf < 5; nf++)
#pragma unroll
            for (int mf = 0; mf < 4; mf++)
                acc[mf][nf] = __builtin_amdgcn_mfma_f32_16x16x32_bf16(a[mf], b[nf], acc[mf][nf], 0, 0, 0);
    }

    __syncthreads();                          // staging reads done -> overlay
#pragma unroll
    for (int p = 0; p < 2; p++) {
#pragma unroll
        for (int mf2 = 0; mf2 < 2; mf2++) {
            int mf = p * 2 + mf2;
#pragma unroll
            for (int nf = 0; nf < 5; nf++)
#pragma unroll
                for (int r = 0; r < 4; r++)
                    sm[(wm * 32 + mf2 * 16 + quad * 4 + r) * 168 + wn * 80 + nf * 16 + lm] =
                        f2bf(acc[mf][nf][r]);
        }
        __syncthreads();
#pragma unroll
        for (int i = 0; i < 5; i++) {
            int slot = tid + i * 256;         // 1280 slots = 64 rows x 20 cgroups
            int lr = slot / 20, cg = slot % 20;
            int grow = m0 + (lr >> 5) * 64 + p * 32 + (lr & 31);
            if (grow < M)
                *(uint4*)(C + (size_t)grow * SP + n0 + cg * 8) =
                    *(const uint4*)(sm + lr * 168 + cg * 8);
        }
        __syncthreads();
    }
}

// ------------------- aggregate + fused BN stats, flat one-node-per-slot -------
__global__ __launch_bounds__(320) void k_aggf(
    const u16* __restrict__ Q, const int* __restrict__ indptr,
    const int* __restrict__ packed, const float* __restrict__ e1,
    const float* __restrict__ e2, u16* __restrict__ P,
    float* __restrict__ colstats, int N) {
    __shared__ float tab[15];
    __shared__ float part[8][328];
    int tid = threadIdx.x;
    if (tid < 15) tab[tid] = e1[tid / 3] + e2[tid % 3];
    __syncthreads();
    int f = tid % 40;
    int slot = tid / 40;
    int n = blockIdx.x * 8 + slot;

    float psum[8] = {0, 0, 0, 0, 0, 0, 0, 0};
    float psq[8]  = {0, 0, 0, 0, 0, 0, 0, 0};

    if (n < N) {
        float acc[8];
        unpack8(*(const uint4*)(Q + (size_t)n * SP + f * 8), acc);
        float s = tab[12];                  // self loop: et=4, ed=0 -> code 12
        int i = indptr[n], e = indptr[n + 1];
        int pk = (i < e) ? packed[i] : 0;
        while (i < e) {
            uint4 g = *(const uint4*)(Q + (size_t)(pk & 0x1FFFF) * SP + f * 8);
            int nx = i + 1;
            int pkn = (nx < e) ? packed[nx] : 0;
            float t[8];
            unpack8(g, t);
#pragma unroll
            for (int q = 0; q < 8; q++) acc[q] += t[q];
            s += tab[pk >> 17];
            i = nx; pk = pkn;
        }
        u32 o[4];
#pragma unroll
        for (int q = 0; q < 4; q++) {
            float r0 = acc[2 * q] + s;
            float r1 = acc[2 * q + 1] + s;
            psum[2 * q] = r0;      psum[2 * q + 1] = r1;
            psq[2 * q]  = r0 * r0; psq[2 * q + 1]  = r1 * r1;
            o[q] = (u32)f2bf(r0) | ((u32)f2bf(r1) << 16);
        }
        *(uint4*)(P + (size_t)n * SP + f * 8) = make_uint4(o[0], o[1], o[2], o[3]);
    }

    int rep = (blockIdx.x & (NREP - 1)) * 2 * SP;
#pragma unroll
    for (int j = 0; j < 8; j++) part[slot][f * 8 + j] = psum[j];
    __syncthreads();
    {
        float s = 0.f;
#pragma unroll
        for (int k = 0; k < 8; k++) s += part[k][tid];
        atomicAdd(&colstats[rep + tid], s);
    }
    __syncthreads();
#pragma unroll
    for (int j = 0; j < 8; j++) part[slot][f * 8 + j] = psq[j];
    __syncthreads();
    {
        float s = 0.f;
#pragma unroll
        for (int k = 0; k < 8; k++) s += part[k][tid];
        atomicAdd(&colstats[rep + SP + tid], s);
    }
}

// ------------------- group boundaries from sorted batch -------------------
__global__ void k_bounds(const int* __restrict__ batch, int* __restrict__ gstart, int N) {
    int n = blockIdx.x * blockDim.x + threadIdx.x;
    if (n > N) return;
    int bcur = (n < N) ? batch[n] : NGRP;
    int bprev = (n > 0) ? batch[n - 1] : -1;
    for (int g = bprev + 1; g <= bcur; g++) gstart[g] = n;
}

// ------------------- pool (BN layer4 fused, no relu), 8 groups/block ----------
__global__ __launch_bounds__(320) void k_pool(
    const u16* __restrict__ P, const float* __restrict__ sc,
    const float* __restrict__ sh, const int* __restrict__ gstart,
    float* __restrict__ hg) {
    int tid = threadIdx.x;
    int g = blockIdx.x * 8 + tid / 40;
    int f = tid % 40;
    int r0 = gstart[g], r1 = gstart[g + 1];
    int cnt = r1 - r0;
    float acc[8] = {0, 0, 0, 0, 0, 0, 0, 0};
    for (int r = r0; r < r1; r++) {
        float t[8];
        unpack8(*(const uint4*)(P + (size_t)r * SP + f * 8), t);
#pragma unroll
        for (int j = 0; j < 8; j++) acc[j] += t[j];
    }
    float inv = 1.f / (float)max(cnt, 1);
#pragma unroll
    for (int j = 0; j < 8; j++) {
        int c = f * 8 + j;
        if (c < EMB)
            hg[(size_t)g * EMB + c] = (acc[j] * sc[c] + (float)cnt * sh[c]) * inv;
    }
}

// ------------------- hf = hg @ feat_W + feat_b -------------------
__global__ __launch_bounds__(256) void k_feat(const float* __restrict__ hg,
                                              const float* __restrict__ fW,
                                              const float* __restrict__ fb,
                                              float* __restrict__ hf) {
    __shared__ float hgs[16 * EMB];
    int g0 = blockIdx.x * 16;
    int tid = threadIdx.x;
    for (int i = tid; i < 16 * EMB; i += 256) {
        int gi = i / EMB, c = i % EMB;
        hgs[i] = hg[(size_t)(g0 + gi) * EMB + c];
    }
    __syncthreads();
    float acc[16];
    float fbv = fb[tid];
#pragma unroll
    for (int gi = 0; gi < 16; gi++) acc[gi] = fbv;
    for (int k = 0; k < EMB; k++) {
        float w = fW[(size_t)k * FEAT + tid];
#pragma unroll
        for (int gi = 0; gi < 16; gi++) acc[gi] += hgs[gi * EMB + k] * w;
    }
#pragma unroll
    for (int gi = 0; gi < 16; gi++) hf[(size_t)(g0 + gi) * FEAT + tid] = acc[gi];
}

// ------------------- head: pred = softplus(hf@W1+b1)@W2+b2 -------------------
__global__ __launch_bounds__(128) void k_head(const float* __restrict__ hf,
                                              const float* __restrict__ W1,
                                              const float* __restrict__ b1,
                                              const float* __restrict__ W2,
                                              const float* __restrict__ b2,
                                              float* __restrict__ pred) {
    __shared__ float hfs[8 * FEAT];
    __shared__ float sred[2][8][2];
    int g0 = blockIdx.x * 8;
    int tid = threadIdx.x;
    for (int i = tid; i < 8 * FEAT; i += 128) {
        int gi = i >> 8, k = i & 255;
        hfs[i] = hf[(size_t)(g0 + gi) * FEAT + k];
    }
    __syncthreads();
    float acc[8];
    float b1v = b1[tid];
#pragma unroll
    for (int gi = 0; gi < 8; gi++) acc[gi] = b1v;
    for (int k = 0; k < FEAT; k++) {
        float w = W1[(size_t)k * 128 + tid];
#pragma unroll
        for (int gi = 0; gi < 8; gi++) acc[gi] += hfs[gi * FEAT + k] * w;
    }
    float w20 = W2[tid * 2], w21 = W2[tid * 2 + 1];
    int wv = tid >> 6;
#pragma unroll
    for (int gi = 0; gi < 8; gi++) {
        float x = acc[gi];
        float t = fmaxf(x, 0.f) + log1pf(expf(-fabsf(x)));
        float p0 = t * w20, p1 = t * w21;
#pragma unroll
        for (int off = 32; off > 0; off >>= 1) {
            p0 += __shfl_down(p0, off);
            p1 += __shfl_down(p1, off);
        }
        if ((tid & 63) == 0) { sred[wv][gi][0] = p0; sred[wv][gi][1] = p1; }
    }
    __syncthreads();
    if (tid < 16) {
        int gi = tid >> 1, o = tid & 1;
        pred[(size_t)(g0 + gi) * 2 + o] = sred[0][gi][o] + sred[1][gi][o] + b2[o];
    }
}

// ------------------- launch -------------------
extern "C" void kernel_launch(void* const* d_in, const int* in_sizes, int n_in,
                              void* d_out, int out_size, void* d_ws, size_t ws_size,
                              hipStream_t stream) {
    const int* atom_type = (const int*)d_in[0];
    const int* chir      = (const int*)d_in[1];
    const int* eidx      = (const int*)d_in[2];
    const int* etype     = (const int*)d_in[3];
    const int* edir      = (const int*)d_in[4];
    const int* batch     = (const int*)d_in[5];
    const float* emb1    = (const float*)d_in[6];
    const float* emb2    = (const float*)d_in[7];
    const float* W       = (const float*)d_in[8];
    const float* ee1     = (const float*)d_in[10];
    const float* ee2     = (const float*)d_in[11];
    const float* gamma   = (const float*)d_in[12];
    const float* beta    = (const float*)d_in[13];
    const float* featW   = (const float*)d_in[14];
    const float* featb   = (const float*)d_in[15];
    const float* hW1     = (const float*)d_in[16];
    const float* hb1     = (const float*)d_in[17];
    const float* hW2     = (const float*)d_in[18];
    const float* hb2     = (const float*)d_in[19];

    int N = in_sizes[0];
    int E = in_sizes[2] / 2;
    const int* erow = eidx;
    const int* ecol = eidx + E;

    size_t off = 0;
    char* base = (char*)d_ws;
    auto carve = [&](size_t bytes) -> void* {
        void* p = base + off;
        off += (bytes + 255) & ~(size_t)255;
        return p;
    };
    u16*   P        = (u16*)  carve((size_t)N * SP * 2);
    u16*   Q        = (u16*)  carve((size_t)N * SP * 2);
    u16*   Wt       = (u16*)  carve((size_t)SP * SP * 2);
    u16*   comb     = (u16*)  carve((size_t)NCOMB * SP * 2);
    int*   c9map    = (int*)  carve((size_t)N * 4);
    int*   deg      = (int*)  carve((size_t)N * 4);
    int*   cursor   = (int*)  carve((size_t)N * 4);
    int*   indptr   = (int*)  carve((size_t)(N + 1) * 4);
    int*   packed   = (int*)  carve((size_t)E * 4);
    int*   bsum     = (int*)  carve(1024 * 4);
    int*   boff     = (int*)  carve(1024 * 4);
    float* cs0      = (float*)carve((size_t)CSB * 4);   // colstats bank 0
    float* cs1      = (float*)carve((size_t)CSB * 4);   // colstats bank 1
    float* scale_bn = (float*)carve(SP * 4);
    float* shift_bn = (float*)carve(SP * 4);
    float* thr_bn   = (float*)carve(SP * 4);
    float* srow     = (float*)carve(SP * 4);
    int*   gstart   = (int*)  carve((size_t)(NGRP + 1) * 4);
    float* hg       = (float*)carve((size_t)NGRP * EMB * 4);

    float* hf   = (float*)d_out;
    float* pred = (float*)d_out + (size_t)NGRP * FEAT;

    int eb = (E + 255) / 256;
    int NB = (N + 1023) / 1024;
    k_prep_n<<<(N + 255) / 256, 256, 0, stream>>>(atom_type, chir, c9map, deg, cursor,
                                                  cs0, N);
    k_count<<<eb, 256, 0, stream>>>(ecol, deg, E);
    k_bsum<<<NB, 256, 0, stream>>>(deg, bsum, N);
    k_scanb<<<1, 128, 0, stream>>>(bsum, boff, NB);
    k_indptr<<<NB, 256, 0, stream>>>(deg, boff, indptr, N);
    k_fill<<<eb, 256, 0, stream>>>(erow, ecol, etype, edir, indptr, cursor, packed, E);

    k_comb<<<(NCOMB * 40 + 255) / 256, 256, 0, stream>>>(emb1, emb2, comb);

    dim3 ggrid(2, (N + MT - 1) / MT);   // x = n-tile, y = m-tile
    int ab = (N + 7) / 8;
    float* banks[2] = {cs0, cs1};
    for (int l = 0; l < 5; l++) {
        float* wb = banks[l & 1];          // bank aggf(l) writes
        float* rb = banks[(l + 1) & 1];    // bank wprep(l) reads (aggf(l-1)'s)
        k_wprep<<<SP, 320, 0, stream>>>(W + (size_t)l * EMB * EMB, rb,
                                        gamma + l * EMB - EMB, beta + l * EMB - EMB,
                                        l == 0 ? 1 : 0, N, Wt, srow, thr_bn);
        if (l == 0)
            k_gemm<<<ggrid, 256, 0, stream>>>(comb, Wt, thr_bn, srow, Q, N, c9map, wb);
        else
            k_gemm<<<ggrid, 256, 0, stream>>>(P, Wt, thr_bn, srow, Q, N, nullptr, wb);
        k_aggf<<<ab, 320, 0, stream>>>(Q, indptr, packed, ee1 + l * 5, ee2 + l * 3, P,
                                       wb, N);
    }

    // layer-4 BN params for the pool (aggf(4) wrote bank 0)
    k_finalize<<<1, SP, 0, stream>>>(banks[4 & 1], gamma + 4 * EMB, beta + 4 * EMB,
                                     scale_bn, shift_bn, N);
    k_bounds<<<(N + 1 + 255) / 256, 256, 0, stream>>>(batch, gstart, N);
    k_pool<<<NGRP / 8, 320, 0, stream>>>(P, scale_bn, shift_bn, gstart, hg);
    k_feat<<<NGRP / 16, 256, 0, stream>>>(hg, featW, featb, hf);
    k_head<<<NGRP / 8, 128, 0, stream>>>(hf, hW1, hb1, hW2, hb2, pred);
}